// Round 5
// baseline (112.508 us; speedup 1.0000x reference)
//
#include <hip/hip_runtime.h>
#include <hip/hip_bf16.h>

constexpr int N_NODES = 50000;
constexpr int DIN     = 256;
constexpr int C_OUT   = 128;
constexpr int E_EDGES = 800000;
constexpr int ET      = E_EDGES + N_NODES;   // with self-loops
constexpr float NEG_SLOPE = 0.2f;

constexpr int GEMM_RPB    = 128;  // rows per block (4 waves x 32)
constexpr int GEMM_BLOCKS = (N_NODES + GEMM_RPB - 1) / GEMM_RPB;  // 391
constexpr int LINK_EPB    = 2048; // edges per link block (256 thr x 8)
constexpr int LINK_BLOCKS = (ET + LINK_EPB - 1) / LINK_EPB;       // 416
constexpr int AGG_NPB     = 32;   // nodes per aggregate block (4 waves x 8)
constexpr int AGG_BLOCKS  = (N_NODES + AGG_NPB - 1) / AGG_NPB;    // 1563

typedef __attribute__((ext_vector_type(8))) short short8v;
typedef __attribute__((ext_vector_type(4))) float f32x4;

static __device__ __forceinline__ ushort f2bf(float f) {
    __hip_bfloat16 b = __float2bfloat16(f);
    return *reinterpret_cast<ushort*>(&b);
}
static __device__ __forceinline__ short f2bfs(float f) {
    __hip_bfloat16 b = __float2bfloat16(f);
    return *reinterpret_cast<short*>(&b);
}

// ---------------------------------------------------------------------------
// K0: Wt -> bf16, fragment-ordered; + head[] = -1.
// fragpos(ks,c,kgrp,col16,j) = ((ks*8+c)*64 + kgrp*16 + col16)*8 + j
//   element W[k][col], k = ks*32+kgrp*8+j, col = c*16+col16.
// ks-block stride = 8*64*8 = 4096 shorts (8 KB) -> phase p covers wt[p*16384..]
// ---------------------------------------------------------------------------
__global__ void wconv_kernel(const float* __restrict__ W, ushort* __restrict__ wt,
                             int* __restrict__ head) {
    const int idx = blockIdx.x * 256 + threadIdx.x;
    if (idx < DIN * C_OUT) {
        const int k = idx >> 7, col = idx & 127;
        const int ks = k >> 5, kgrp = (k >> 3) & 3, j = k & 7;
        const int c = col >> 4, col16 = col & 15;
        const int fragpos = ((ks * 8 + c) * 64 + kgrp * 16 + col16) * 8 + j;
        wt[fragpos] = f2bf(W[idx]);
    }
    if (idx < N_NODES) head[idx] = -1;
}

// ---------------------------------------------------------------------------
// K1: linked-list grouping by destination: nxt2[e] = {prev_head, src}.
// ---------------------------------------------------------------------------
__global__ __launch_bounds__(256) void link_kernel(const int* __restrict__ ei,
                                                   int* __restrict__ head,
                                                   int2* __restrict__ nxt2) {
    const int b = blockIdx.x;
    #pragma unroll
    for (int i = 0; i < 8; i++) {
        const int e = b * LINK_EPB + i * 256 + threadIdx.x;
        if (e < ET) {
            int s, d;
            if (e < E_EDGES) { s = ei[e]; d = ei[E_EDGES + e]; }
            else             { s = e - E_EDGES; d = s; }
            const int old = atomicExch(&head[d], e);
            nxt2[e] = make_int2(old, s);
        }
    }
}

// ---------------------------------------------------------------------------
// K2: h = x@W via MFMA; Wt staged in LDS 32 KB per K-half (occupancy-friendly).
//     4 waves x 32 rows = 128 rows/block. Epilogue fuses att dot products.
// ---------------------------------------------------------------------------
__global__ __launch_bounds__(256) void gemm_mfma(const float* __restrict__ x,
                                                 const ushort* __restrict__ wt,
                                                 const float* __restrict__ att,
                                                 ushort* __restrict__ hb,
                                                 float* __restrict__ s_dst,
                                                 float* __restrict__ s_src) {
    __shared__ ushort lw[DIN * C_OUT / 2];   // 32 KB, one K-half fragment-ordered
    const int t = threadIdx.x;
    const int lane = t & 63, wv = t >> 6;
    const int col16 = lane & 15, kgrp = lane >> 4;
    const int rowbase = blockIdx.x * GEMM_RPB + wv * 32;
    int r0 = rowbase + col16;      if (r0 >= N_NODES) r0 = N_NODES - 1;
    int r1 = rowbase + 16 + col16; if (r1 >= N_NODES) r1 = N_NODES - 1;
    const float* xr0 = x + (size_t)r0 * DIN + kgrp * 8;
    const float* xr1 = x + (size_t)r1 * DIN + kgrp * 8;

    f32x4 acc[2][8] = {};
    const short8v* lwf = (const short8v*)lw;
    #pragma unroll
    for (int ph = 0; ph < 2; ph++) {
        if (ph) __syncthreads();             // protect LDS before overwrite
        {   // stage this K-half (32 KB contiguous)
            const uint4* src = (const uint4*)(wt + ph * (DIN * C_OUT / 2));
            uint4* dst = (uint4*)lw;
            #pragma unroll
            for (int i = 0; i < 8; i++) dst[t + i * 256] = src[t + i * 256];
        }
        __syncthreads();
        #pragma unroll
        for (int ks = 0; ks < 4; ks++) {
            const int kg = ph * 4 + ks;      // global k-slice
            const float4 v0 = *(const float4*)(xr0 + kg * 32);
            const float4 v1 = *(const float4*)(xr0 + kg * 32 + 4);
            const float4 u0 = *(const float4*)(xr1 + kg * 32);
            const float4 u1 = *(const float4*)(xr1 + kg * 32 + 4);
            short8v a0, a1;
            a0[0] = f2bfs(v0.x); a0[1] = f2bfs(v0.y); a0[2] = f2bfs(v0.z); a0[3] = f2bfs(v0.w);
            a0[4] = f2bfs(v1.x); a0[5] = f2bfs(v1.y); a0[6] = f2bfs(v1.z); a0[7] = f2bfs(v1.w);
            a1[0] = f2bfs(u0.x); a1[1] = f2bfs(u0.y); a1[2] = f2bfs(u0.z); a1[3] = f2bfs(u0.w);
            a1[4] = f2bfs(u1.x); a1[5] = f2bfs(u1.y); a1[6] = f2bfs(u1.z); a1[7] = f2bfs(u1.w);
            #pragma unroll
            for (int c = 0; c < 8; c++) {
                const short8v bfr = lwf[(ks * 8 + c) * 64 + lane];
                acc[0][c] = __builtin_amdgcn_mfma_f32_16x16x32_bf16(a0, bfr, acc[0][c], 0, 0, 0);
                acc[1][c] = __builtin_amdgcn_mfma_f32_16x16x32_bf16(a1, bfr, acc[1][c], 0, 0, 0);
            }
        }
    }

    // epilogue: h (bf16) + fused att dot products
    float attd[8], atts[8];
    #pragma unroll
    for (int c = 0; c < 8; c++) {
        attd[c] = att[c * 16 + col16];
        atts[c] = att[C_OUT + c * 16 + col16];
    }
    #pragma unroll
    for (int rs = 0; rs < 2; rs++) {
        #pragma unroll
        for (int j = 0; j < 4; j++) {
            const int row = rowbase + rs * 16 + kgrp * 4 + j;  // C/D: col=lane&15, row=(lane>>4)*4+j
            const bool ok = (row < N_NODES);
            float pd = 0.f, ps = 0.f;
            #pragma unroll
            for (int c = 0; c < 8; c++) {
                const float hv = acc[rs][c][j];
                pd += hv * attd[c];
                ps += hv * atts[c];
                if (ok) hb[(size_t)row * C_OUT + c * 16 + col16] = f2bf(hv);
            }
            #pragma unroll
            for (int off = 1; off < 16; off <<= 1) {
                pd += __shfl_xor(pd, off);
                ps += __shfl_xor(ps, off);
            }
            if (col16 == 0 && ok) { s_dst[row] = pd; s_src[row] = ps; }
        }
    }
}

// ---------------------------------------------------------------------------
// K3: aggregation by chain-walk. 8 nodes per wave (8-lane groups; each lane
// holds 2x uint4 = full 256 B bf16 row per group) -> 8 independent chains in
// flight per wave. src packed in nxt2 (no ei gathers). Softmax without
// max-subtraction (|alpha| small, fp32-safe, ratios exact).
// ---------------------------------------------------------------------------
__global__ __launch_bounds__(256) void aggregate_kernel(
    const ushort* __restrict__ hb, const int* __restrict__ head,
    const int2* __restrict__ nxt2, const float* __restrict__ s_dst,
    const float* __restrict__ s_src, const float* __restrict__ bias,
    float* __restrict__ out) {
    const int t = threadIdx.x;
    const int wv = t >> 6, lane = t & 63;
    const int sub = lane >> 3, l8 = lane & 7;          // 8 groups of 8 lanes
    const int node = blockIdx.x * AGG_NPB + wv * 8 + sub;
    const bool valid = (node < N_NODES);

    const float sd = valid ? s_dst[node] : 0.f;
    int e = valid ? head[node] : -1;
    float den = 0.f;
    float acc[16] = {};
    const uint4* __restrict__ h4 = (const uint4*)hb;

    while (__ballot(e >= 0)) {
        if (e >= 0) {
            const int2 ns = nxt2[e];
            const int s = ns.y;
            e = ns.x;
            float a = sd + s_src[s];
            a = (a > 0.f) ? a : NEG_SLOPE * a;
            const float w = __expf(a);
            den += w;
            const uint4 hv0 = h4[(size_t)s * 16 + l8];
            const uint4 hv1 = h4[(size_t)s * 16 + 8 + l8];
            acc[0]  += w * __uint_as_float(hv0.x << 16);
            acc[1]  += w * __uint_as_float(hv0.x & 0xffff0000u);
            acc[2]  += w * __uint_as_float(hv0.y << 16);
            acc[3]  += w * __uint_as_float(hv0.y & 0xffff0000u);
            acc[4]  += w * __uint_as_float(hv0.z << 16);
            acc[5]  += w * __uint_as_float(hv0.z & 0xffff0000u);
            acc[6]  += w * __uint_as_float(hv0.w << 16);
            acc[7]  += w * __uint_as_float(hv0.w & 0xffff0000u);
            acc[8]  += w * __uint_as_float(hv1.x << 16);
            acc[9]  += w * __uint_as_float(hv1.x & 0xffff0000u);
            acc[10] += w * __uint_as_float(hv1.y << 16);
            acc[11] += w * __uint_as_float(hv1.y & 0xffff0000u);
            acc[12] += w * __uint_as_float(hv1.z << 16);
            acc[13] += w * __uint_as_float(hv1.z & 0xffff0000u);
            acc[14] += w * __uint_as_float(hv1.w << 16);
            acc[15] += w * __uint_as_float(hv1.w & 0xffff0000u);
        }
    }
    if (!valid) return;
    const float inv = 1.f / (den + 1e-16f);
    float* op = out + (size_t)node * C_OUT;
    #pragma unroll
    for (int half = 0; half < 2; half++) {
        const int base = half * 64 + l8 * 8;
        const float4 b0 = *(const float4*)(bias + base);
        const float4 b1 = *(const float4*)(bias + base + 4);
        float4 o0 = make_float4(acc[half * 8 + 0] * inv + b0.x, acc[half * 8 + 1] * inv + b0.y,
                                acc[half * 8 + 2] * inv + b0.z, acc[half * 8 + 3] * inv + b0.w);
        float4 o1 = make_float4(acc[half * 8 + 4] * inv + b1.x, acc[half * 8 + 5] * inv + b1.y,
                                acc[half * 8 + 6] * inv + b1.z, acc[half * 8 + 7] * inv + b1.w);
        *(float4*)(op + base)     = o0;
        *(float4*)(op + base + 4) = o1;
    }
}

// ---------------------------------------------------------------------------
extern "C" void kernel_launch(void* const* d_in, const int* in_sizes, int n_in,
                              void* d_out, int out_size, void* d_ws, size_t ws_size,
                              hipStream_t stream) {
    const float* x    = (const float*)d_in[0];
    const int*   ei   = (const int*)d_in[1];
    const float* W    = (const float*)d_in[2];
    const float* att  = (const float*)d_in[3];
    const float* bias = (const float*)d_in[4];
    float* out = (float*)d_out;

    // workspace layout (~20 MB); wt first for 16 B alignment
    ushort* wt    = (ushort*)d_ws;                          // 32768 (64 KB)
    ushort* hbuf  = wt + DIN * C_OUT;                       // N*128 bf16 (12.8 MB)
    float*  s_src = (float*)(hbuf + (size_t)N_NODES * C_OUT);
    float*  s_dst = s_src + N_NODES;
    int*    head  = (int*)(s_dst + N_NODES);                // N
    int2*   nxt2  = (int2*)(head + N_NODES);                // ET int2 (6.8 MB), 8B-aligned

    wconv_kernel<<<(N_NODES + 255) / 256, 256, 0, stream>>>(W, wt, head);
    link_kernel<<<LINK_BLOCKS, 256, 0, stream>>>(ei, head, nxt2);
    gemm_mfma<<<GEMM_BLOCKS, 256, 0, stream>>>(x, wt, att, hbuf, s_dst, s_src);
    aggregate_kernel<<<AGG_BLOCKS, 256, 0, stream>>>(
        hbuf, head, nxt2, s_dst, s_src, bias, out);
}

// Round 6
// 112.393 us; speedup vs baseline: 1.0010x; 1.0010x over previous
//
#include <hip/hip_runtime.h>
#include <hip/hip_bf16.h>

constexpr int N_NODES = 50000;
constexpr int DIN     = 256;
constexpr int C_OUT   = 128;
constexpr int E_EDGES = 800000;
constexpr int ET      = E_EDGES + N_NODES;   // with self-loops
constexpr float NEG_SLOPE = 0.2f;

constexpr int GEMM_RPB    = 128;  // rows per block (4 waves x 32)
constexpr int GEMM_BLOCKS = (N_NODES + GEMM_RPB - 1) / GEMM_RPB;  // 391
constexpr int LINK_EPB    = 2048; // edges per link block (256 thr x 8)
constexpr int LINK_BLOCKS = (ET + LINK_EPB - 1) / LINK_EPB;       // 416
constexpr int WCONV_BLOCKS = (DIN * C_OUT) / 256;                 // 128
constexpr int XCONV_BLOCKS = (N_NODES * DIN) / 8 / 256;           // 6250
constexpr int AGG_NPB     = 32;   // nodes per aggregate block (4 waves x 8)
constexpr int AGG_BLOCKS  = (N_NODES + AGG_NPB - 1) / AGG_NPB;    // 1563

typedef __attribute__((ext_vector_type(8))) short short8v;
typedef __attribute__((ext_vector_type(4))) float f32x4;

static __device__ __forceinline__ ushort f2bf(float f) {
    __hip_bfloat16 b = __float2bfloat16(f);
    return *reinterpret_cast<ushort*>(&b);
}
static __device__ __forceinline__ short f2bfs(float f) {
    __hip_bfloat16 b = __float2bfloat16(f);
    return *reinterpret_cast<short*>(&b);
}

// ---------------------------------------------------------------------------
// K1 (fused prep): three independent block roles in one dispatch so the
// atomic-latency-bound link work overlaps the BW-bound conversions.
//  [0, LINK)              : nxt2[e] = {atomicExch(&head[dst],e), src}
//  [LINK, LINK+WCONV)     : Wt -> bf16, fragment-ordered
//  [LINK+WCONV, +XCONV)   : x -> bf16 (streaming, 8 elems/thread)
// fragpos(ks,c,kgrp,col16,j) = ((ks*8+c)*64 + kgrp*16 + col16)*8 + j
//   element W[k][col], k = ks*32+kgrp*8+j, col = c*16+col16.
// ---------------------------------------------------------------------------
__global__ __launch_bounds__(256) void prep_kernel(const float* __restrict__ x,
                                                   const float* __restrict__ W,
                                                   const int* __restrict__ ei,
                                                   ushort* __restrict__ wt,
                                                   ushort* __restrict__ xb,
                                                   int* __restrict__ head,
                                                   int2* __restrict__ nxt2) {
    const int t = threadIdx.x;
    if (blockIdx.x < LINK_BLOCKS) {
        const int b = blockIdx.x;
        #pragma unroll
        for (int i = 0; i < 8; i++) {
            const int e = b * LINK_EPB + i * 256 + t;
            if (e < ET) {
                int s, d;
                if (e < E_EDGES) { s = ei[e]; d = ei[E_EDGES + e]; }
                else             { s = e - E_EDGES; d = s; }
                const int old = atomicExch(&head[d], e);
                nxt2[e] = make_int2(old, s);
            }
        }
        return;
    }
    if (blockIdx.x < LINK_BLOCKS + WCONV_BLOCKS) {
        const int idx = (blockIdx.x - LINK_BLOCKS) * 256 + t;
        const int k = idx >> 7, col = idx & 127;
        const int ks = k >> 5, kgrp = (k >> 3) & 3, j = k & 7;
        const int c = col >> 4, col16 = col & 15;
        wt[((ks * 8 + c) * 64 + kgrp * 16 + col16) * 8 + j] = f2bf(W[idx]);
        return;
    }
    // x -> bf16 streaming conversion
    const size_t i = ((size_t)(blockIdx.x - LINK_BLOCKS - WCONV_BLOCKS) * 256 + t) * 8;
    const float4 a = *(const float4*)(x + i);
    const float4 b = *(const float4*)(x + i + 4);
    short8v v;
    v[0] = f2bfs(a.x); v[1] = f2bfs(a.y); v[2] = f2bfs(a.z); v[3] = f2bfs(a.w);
    v[4] = f2bfs(b.x); v[5] = f2bfs(b.y); v[6] = f2bfs(b.z); v[7] = f2bfs(b.w);
    *(short8v*)(xb + i) = v;
}

// ---------------------------------------------------------------------------
// K2: h = x@W via MFMA. A-fragments are direct 16 B bf16 loads (hoisted per
// K-half, 8 in flight/lane); B staged in 32 KB LDS per K-half.
// ---------------------------------------------------------------------------
__global__ __launch_bounds__(256) void gemm_mfma(const ushort* __restrict__ xb,
                                                 const ushort* __restrict__ wt,
                                                 const float* __restrict__ att,
                                                 ushort* __restrict__ hb,
                                                 float* __restrict__ s_dst,
                                                 float* __restrict__ s_src) {
    __shared__ ushort lw[DIN * C_OUT / 2];   // 32 KB, one K-half fragment-ordered
    const int t = threadIdx.x;
    const int lane = t & 63, wv = t >> 6;
    const int col16 = lane & 15, kgrp = lane >> 4;
    const int rowbase = blockIdx.x * GEMM_RPB + wv * 32;
    int r0 = rowbase + col16;      if (r0 >= N_NODES) r0 = N_NODES - 1;
    int r1 = rowbase + 16 + col16; if (r1 >= N_NODES) r1 = N_NODES - 1;
    // row = 32 x short8v; fragment for (kg,kgrp) at index kg*4 + kgrp
    const short8v* x0 = (const short8v*)(xb + (size_t)r0 * DIN);
    const short8v* x1 = (const short8v*)(xb + (size_t)r1 * DIN);

    f32x4 acc[2][8] = {};
    const short8v* lwf = (const short8v*)lw;
    #pragma unroll
    for (int ph = 0; ph < 2; ph++) {
        if (ph) __syncthreads();             // protect LDS before overwrite
        {   // stage this K-half of Wt (32 KB contiguous)
            const uint4* src = (const uint4*)(wt + ph * (DIN * C_OUT / 2));
            uint4* dst = (uint4*)lw;
            #pragma unroll
            for (int i = 0; i < 8; i++) dst[t + i * 256] = src[t + i * 256];
        }
        // hoisted A-fragment loads for this K-half (independent of LDS)
        short8v A0[4], A1[4];
        #pragma unroll
        for (int ks = 0; ks < 4; ks++) {
            A0[ks] = x0[(ph * 4 + ks) * 4 + kgrp];
            A1[ks] = x1[(ph * 4 + ks) * 4 + kgrp];
        }
        __syncthreads();
        #pragma unroll
        for (int ks = 0; ks < 4; ks++) {
            #pragma unroll
            for (int c = 0; c < 8; c++) {
                const short8v bfr = lwf[(ks * 8 + c) * 64 + lane];
                acc[0][c] = __builtin_amdgcn_mfma_f32_16x16x32_bf16(A0[ks], bfr, acc[0][c], 0, 0, 0);
                acc[1][c] = __builtin_amdgcn_mfma_f32_16x16x32_bf16(A1[ks], bfr, acc[1][c], 0, 0, 0);
            }
        }
    }

    // epilogue: h (bf16) + fused att dot products
    float attd[8], atts[8];
    #pragma unroll
    for (int c = 0; c < 8; c++) {
        attd[c] = att[c * 16 + col16];
        atts[c] = att[C_OUT + c * 16 + col16];
    }
    #pragma unroll
    for (int rs = 0; rs < 2; rs++) {
        #pragma unroll
        for (int j = 0; j < 4; j++) {
            const int row = rowbase + rs * 16 + kgrp * 4 + j;  // C/D: col=lane&15, row=(lane>>4)*4+j
            const bool ok = (row < N_NODES);
            float pd = 0.f, ps = 0.f;
            #pragma unroll
            for (int c = 0; c < 8; c++) {
                const float hv = acc[rs][c][j];
                pd += hv * attd[c];
                ps += hv * atts[c];
                if (ok) hb[(size_t)row * C_OUT + c * 16 + col16] = f2bf(hv);
            }
            #pragma unroll
            for (int off = 1; off < 16; off <<= 1) {
                pd += __shfl_xor(pd, off);
                ps += __shfl_xor(ps, off);
            }
            if (col16 == 0 && ok) { s_dst[row] = pd; s_src[row] = ps; }
        }
    }
}

// ---------------------------------------------------------------------------
// K3: aggregation by chain-walk. 8 nodes per wave (8-lane groups; each lane
// holds 2x uint4 = full 256 B bf16 row per group) -> 8 independent chains in
// flight per wave. src packed in nxt2. Softmax without max-subtraction
// (|alpha| small, fp32-safe, ratios exact).
// ---------------------------------------------------------------------------
__global__ __launch_bounds__(256) void aggregate_kernel(
    const ushort* __restrict__ hb, const int* __restrict__ head,
    const int2* __restrict__ nxt2, const float* __restrict__ s_dst,
    const float* __restrict__ s_src, const float* __restrict__ bias,
    float* __restrict__ out) {
    const int t = threadIdx.x;
    const int wv = t >> 6, lane = t & 63;
    const int sub = lane >> 3, l8 = lane & 7;          // 8 groups of 8 lanes
    const int node = blockIdx.x * AGG_NPB + wv * 8 + sub;
    const bool valid = (node < N_NODES);

    const float sd = valid ? s_dst[node] : 0.f;
    int e = valid ? head[node] : -1;
    float den = 0.f;
    float acc[16] = {};
    const uint4* __restrict__ h4 = (const uint4*)hb;

    while (__ballot(e >= 0)) {
        if (e >= 0) {
            const int2 ns = nxt2[e];
            const int s = ns.y;
            e = ns.x;
            float a = sd + s_src[s];
            a = (a > 0.f) ? a : NEG_SLOPE * a;
            const float w = __expf(a);
            den += w;
            const uint4 hv0 = h4[(size_t)s * 16 + l8];
            const uint4 hv1 = h4[(size_t)s * 16 + 8 + l8];
            acc[0]  += w * __uint_as_float(hv0.x << 16);
            acc[1]  += w * __uint_as_float(hv0.x & 0xffff0000u);
            acc[2]  += w * __uint_as_float(hv0.y << 16);
            acc[3]  += w * __uint_as_float(hv0.y & 0xffff0000u);
            acc[4]  += w * __uint_as_float(hv0.z << 16);
            acc[5]  += w * __uint_as_float(hv0.z & 0xffff0000u);
            acc[6]  += w * __uint_as_float(hv0.w << 16);
            acc[7]  += w * __uint_as_float(hv0.w & 0xffff0000u);
            acc[8]  += w * __uint_as_float(hv1.x << 16);
            acc[9]  += w * __uint_as_float(hv1.x & 0xffff0000u);
            acc[10] += w * __uint_as_float(hv1.y << 16);
            acc[11] += w * __uint_as_float(hv1.y & 0xffff0000u);
            acc[12] += w * __uint_as_float(hv1.z << 16);
            acc[13] += w * __uint_as_float(hv1.z & 0xffff0000u);
            acc[14] += w * __uint_as_float(hv1.w << 16);
            acc[15] += w * __uint_as_float(hv1.w & 0xffff0000u);
        }
    }
    if (!valid) return;
    const float inv = 1.f / (den + 1e-16f);
    float* op = out + (size_t)node * C_OUT;
    #pragma unroll
    for (int half = 0; half < 2; half++) {
        const int base = half * 64 + l8 * 8;
        const float4 b0 = *(const float4*)(bias + base);
        const float4 b1 = *(const float4*)(bias + base + 4);
        float4 o0 = make_float4(acc[half * 8 + 0] * inv + b0.x, acc[half * 8 + 1] * inv + b0.y,
                                acc[half * 8 + 2] * inv + b0.z, acc[half * 8 + 3] * inv + b0.w);
        float4 o1 = make_float4(acc[half * 8 + 4] * inv + b1.x, acc[half * 8 + 5] * inv + b1.y,
                                acc[half * 8 + 6] * inv + b1.z, acc[half * 8 + 7] * inv + b1.w);
        *(float4*)(op + base)     = o0;
        *(float4*)(op + base + 4) = o1;
    }
}

// ---------------------------------------------------------------------------
extern "C" void kernel_launch(void* const* d_in, const int* in_sizes, int n_in,
                              void* d_out, int out_size, void* d_ws, size_t ws_size,
                              hipStream_t stream) {
    const float* x    = (const float*)d_in[0];
    const int*   ei   = (const int*)d_in[1];
    const float* W    = (const float*)d_in[2];
    const float* att  = (const float*)d_in[3];
    const float* bias = (const float*)d_in[4];
    float* out = (float*)d_out;

    // workspace layout (~46 MB); wt first for 16 B alignment
    ushort* wt    = (ushort*)d_ws;                          // 32768 (64 KB)
    ushort* xb    = wt + DIN * C_OUT;                       // N*256 bf16 (25.6 MB)
    ushort* hbuf  = xb + (size_t)N_NODES * DIN;             // N*128 bf16 (12.8 MB)
    float*  s_src = (float*)(hbuf + (size_t)N_NODES * C_OUT);
    float*  s_dst = s_src + N_NODES;
    int*    head  = (int*)(s_dst + N_NODES);                // N
    int2*   nxt2  = (int2*)(head + N_NODES);                // ET int2 (6.8 MB), 8B-aligned

    hipMemsetAsync(head, 0xFF, N_NODES * sizeof(int), stream);   // head[i] = -1
    prep_kernel<<<LINK_BLOCKS + WCONV_BLOCKS + XCONV_BLOCKS, 256, 0, stream>>>(
        x, W, ei, wt, xb, head, nxt2);
    gemm_mfma<<<GEMM_BLOCKS, 256, 0, stream>>>(xb, wt, att, hbuf, s_dst, s_src);
    aggregate_kernel<<<AGG_BLOCKS, 256, 0, stream>>>(
        hbuf, head, nxt2, s_dst, s_src, bias, out);
}

// Round 7
// 100.327 us; speedup vs baseline: 1.1214x; 1.1203x over previous
//
#include <hip/hip_runtime.h>
#include <hip/hip_bf16.h>

constexpr int N_NODES = 50000;
constexpr int DIN     = 256;
constexpr int C_OUT   = 128;
constexpr int E_EDGES = 800000;
constexpr int ET      = E_EDGES + N_NODES;   // with self-loops
constexpr float NEG_SLOPE = 0.2f;

constexpr int GEMM_RPB    = 64;   // rows per block (4 waves x 16)
constexpr int GEMM_BLOCKS = (N_NODES + GEMM_RPB - 1) / GEMM_RPB;  // 782 (~3/CU)
constexpr int LINK_EPB    = 2048; // edges per link block (256 thr x 8)
constexpr int LINK_BLOCKS = (ET + LINK_EPB - 1) / LINK_EPB;       // 416
constexpr int AGG_NPB     = 32;   // nodes per aggregate block (4 waves x 8)
constexpr int AGG_BLOCKS  = (N_NODES + AGG_NPB - 1) / AGG_NPB;    // 1563

typedef __attribute__((ext_vector_type(8))) short short8v;
typedef __attribute__((ext_vector_type(4))) float f32x4;

static __device__ __forceinline__ ushort f2bf(float f) {
    __hip_bfloat16 b = __float2bfloat16(f);
    return *reinterpret_cast<ushort*>(&b);
}
static __device__ __forceinline__ short f2bfs(float f) {
    __hip_bfloat16 b = __float2bfloat16(f);
    return *reinterpret_cast<short*>(&b);
}

// ---------------------------------------------------------------------------
// K0: Wt -> bf16 fragment-ordered  +  head[] = -1  (fused, one dispatch).
// fragpos(ks,c,kgrp,col16,j) = ((ks*8+c)*64 + kgrp*16 + col16)*8 + j
//   element W[k][col], k = ks*32+kgrp*8+j, col = c*16+col16.
// ---------------------------------------------------------------------------
__global__ __launch_bounds__(256) void wconv_kernel(const float* __restrict__ W,
                                                    ushort* __restrict__ wt,
                                                    int* __restrict__ head) {
    const int idx = blockIdx.x * 256 + threadIdx.x;
    if (idx < DIN * C_OUT) {
        const int k = idx >> 7, col = idx & 127;
        const int ks = k >> 5, kgrp = (k >> 3) & 3, j = k & 7;
        const int c = col >> 4, col16 = col & 15;
        wt[((ks * 8 + c) * 64 + kgrp * 16 + col16) * 8 + j] = f2bf(W[idx]);
    }
    if (idx < N_NODES) head[idx] = -1;
}

// ---------------------------------------------------------------------------
// K1 (fused): blocks [0, LINK_BLOCKS): linked-list build
//                 nxt2[e] = {atomicExch(&head[dst], e), src}  (link FIRST so
//                 its atomic latency overlaps the gemm blocks behind it);
//             blocks [LINK_BLOCKS, +GEMM_BLOCKS): h = x@W via MFMA.
//                 x read fp32 directly, cvt to bf16 frags in registers;
//                 Wt staged 32 KB per K-half in LDS. 4 waves x 16 rows.
//                 Epilogue fuses s_dst/s_src = h . att, h stored bf16.
// ---------------------------------------------------------------------------
__global__ __launch_bounds__(256) void gemm_link(const float* __restrict__ x,
                                                 const ushort* __restrict__ wt,
                                                 const float* __restrict__ att,
                                                 const int* __restrict__ ei,
                                                 ushort* __restrict__ hb,
                                                 float* __restrict__ s_dst,
                                                 float* __restrict__ s_src,
                                                 int* __restrict__ head,
                                                 int2* __restrict__ nxt2) {
    __shared__ ushort lw[DIN * C_OUT / 2];   // 32 KB, one K-half fragment-ordered
    const int t = threadIdx.x;

    if (blockIdx.x < LINK_BLOCKS) {          // ---- linked-list build path ----
        const int b = blockIdx.x;
        #pragma unroll
        for (int i = 0; i < 8; i++) {
            const int e = b * LINK_EPB + i * 256 + t;
            if (e < ET) {
                int s, d;
                if (e < E_EDGES) { s = ei[e]; d = ei[E_EDGES + e]; }
                else             { s = e - E_EDGES; d = s; }
                const int old = atomicExch(&head[d], e);
                nxt2[e] = make_int2(old, s);
            }
        }
        return;
    }

    // ---- GEMM path ----
    const int gb = blockIdx.x - LINK_BLOCKS;
    const int lane = t & 63, wv = t >> 6;
    const int col16 = lane & 15, kgrp = lane >> 4;
    const int rowbase = gb * GEMM_RPB + wv * 16;
    int r0 = rowbase + col16; if (r0 >= N_NODES) r0 = N_NODES - 1;
    const float* xr0 = x + (size_t)r0 * DIN + kgrp * 8;

    f32x4 acc[8] = {};
    const short8v* lwf = (const short8v*)lw;
    #pragma unroll
    for (int ph = 0; ph < 2; ph++) {
        if (ph) __syncthreads();             // protect LDS before overwrite
        {   // stage this K-half of Wt (32 KB contiguous)
            const uint4* src = (const uint4*)(wt + ph * (DIN * C_OUT / 2));
            uint4* dst = (uint4*)lw;
            #pragma unroll
            for (int i = 0; i < 8; i++) dst[t + i * 256] = src[t + i * 256];
        }
        // hoisted fp32 A loads + in-register bf16 cvt (independent of LDS)
        short8v A0[4];
        #pragma unroll
        for (int ks = 0; ks < 4; ks++) {
            const int kg = ph * 4 + ks;
            const float4 v0 = *(const float4*)(xr0 + kg * 32);
            const float4 v1 = *(const float4*)(xr0 + kg * 32 + 4);
            short8v a;
            a[0] = f2bfs(v0.x); a[1] = f2bfs(v0.y); a[2] = f2bfs(v0.z); a[3] = f2bfs(v0.w);
            a[4] = f2bfs(v1.x); a[5] = f2bfs(v1.y); a[6] = f2bfs(v1.z); a[7] = f2bfs(v1.w);
            A0[ks] = a;
        }
        __syncthreads();
        #pragma unroll
        for (int ks = 0; ks < 4; ks++) {
            #pragma unroll
            for (int c = 0; c < 8; c++) {
                const short8v bfr = lwf[(ks * 8 + c) * 64 + lane];
                acc[c] = __builtin_amdgcn_mfma_f32_16x16x32_bf16(A0[ks], bfr, acc[c], 0, 0, 0);
            }
        }
    }

    // epilogue: h (bf16) + fused att dot products
    float attd[8], atts[8];
    #pragma unroll
    for (int c = 0; c < 8; c++) {
        attd[c] = att[c * 16 + col16];
        atts[c] = att[C_OUT + c * 16 + col16];
    }
    #pragma unroll
    for (int j = 0; j < 4; j++) {
        const int row = rowbase + kgrp * 4 + j;   // C/D: col=lane&15, row=(lane>>4)*4+j
        const bool ok = (row < N_NODES);
        float pd = 0.f, ps = 0.f;
        #pragma unroll
        for (int c = 0; c < 8; c++) {
            const float hv = acc[c][j];
            pd += hv * attd[c];
            ps += hv * atts[c];
            if (ok) hb[(size_t)row * C_OUT + c * 16 + col16] = f2bf(hv);
        }
        #pragma unroll
        for (int off = 1; off < 16; off <<= 1) {
            pd += __shfl_xor(pd, off);
            ps += __shfl_xor(ps, off);
        }
        if (col16 == 0 && ok) { s_dst[row] = pd; s_src[row] = ps; }
    }
}

// ---------------------------------------------------------------------------
// K2: aggregation by chain-walk. 8 nodes per wave (8-lane groups; each lane
// holds 2x uint4 = full 256 B bf16 row per group) -> 8 independent chains in
// flight per wave. src packed in nxt2. Softmax without max-subtraction
// (|alpha| small, fp32-safe, ratios exact).
// ---------------------------------------------------------------------------
__global__ __launch_bounds__(256) void aggregate_kernel(
    const ushort* __restrict__ hb, const int* __restrict__ head,
    const int2* __restrict__ nxt2, const float* __restrict__ s_dst,
    const float* __restrict__ s_src, const float* __restrict__ bias,
    float* __restrict__ out) {
    const int t = threadIdx.x;
    const int wv = t >> 6, lane = t & 63;
    const int sub = lane >> 3, l8 = lane & 7;          // 8 groups of 8 lanes
    const int node = blockIdx.x * AGG_NPB + wv * 8 + sub;
    const bool valid = (node < N_NODES);

    const float sd = valid ? s_dst[node] : 0.f;
    int e = valid ? head[node] : -1;
    float den = 0.f;
    float acc[16] = {};
    const uint4* __restrict__ h4 = (const uint4*)hb;

    while (__ballot(e >= 0)) {
        if (e >= 0) {
            const int2 ns = nxt2[e];
            const int s = ns.y;
            e = ns.x;
            float a = sd + s_src[s];
            a = (a > 0.f) ? a : NEG_SLOPE * a;
            const float w = __expf(a);
            den += w;
            const uint4 hv0 = h4[(size_t)s * 16 + l8];
            const uint4 hv1 = h4[(size_t)s * 16 + 8 + l8];
            acc[0]  += w * __uint_as_float(hv0.x << 16);
            acc[1]  += w * __uint_as_float(hv0.x & 0xffff0000u);
            acc[2]  += w * __uint_as_float(hv0.y << 16);
            acc[3]  += w * __uint_as_float(hv0.y & 0xffff0000u);
            acc[4]  += w * __uint_as_float(hv0.z << 16);
            acc[5]  += w * __uint_as_float(hv0.z & 0xffff0000u);
            acc[6]  += w * __uint_as_float(hv0.w << 16);
            acc[7]  += w * __uint_as_float(hv0.w & 0xffff0000u);
            acc[8]  += w * __uint_as_float(hv1.x << 16);
            acc[9]  += w * __uint_as_float(hv1.x & 0xffff0000u);
            acc[10] += w * __uint_as_float(hv1.y << 16);
            acc[11] += w * __uint_as_float(hv1.y & 0xffff0000u);
            acc[12] += w * __uint_as_float(hv1.z << 16);
            acc[13] += w * __uint_as_float(hv1.z & 0xffff0000u);
            acc[14] += w * __uint_as_float(hv1.w << 16);
            acc[15] += w * __uint_as_float(hv1.w & 0xffff0000u);
        }
    }
    if (!valid) return;
    const float inv = 1.f / (den + 1e-16f);
    float* op = out + (size_t)node * C_OUT;
    #pragma unroll
    for (int half = 0; half < 2; half++) {
        const int base = half * 64 + l8 * 8;
        const float4 b0 = *(const float4*)(bias + base);
        const float4 b1 = *(const float4*)(bias + base + 4);
        float4 o0 = make_float4(acc[half * 8 + 0] * inv + b0.x, acc[half * 8 + 1] * inv + b0.y,
                                acc[half * 8 + 2] * inv + b0.z, acc[half * 8 + 3] * inv + b0.w);
        float4 o1 = make_float4(acc[half * 8 + 4] * inv + b1.x, acc[half * 8 + 5] * inv + b1.y,
                                acc[half * 8 + 6] * inv + b1.z, acc[half * 8 + 7] * inv + b1.w);
        *(float4*)(op + base)     = o0;
        *(float4*)(op + base + 4) = o1;
    }
}

// ---------------------------------------------------------------------------
extern "C" void kernel_launch(void* const* d_in, const int* in_sizes, int n_in,
                              void* d_out, int out_size, void* d_ws, size_t ws_size,
                              hipStream_t stream) {
    const float* x    = (const float*)d_in[0];
    const int*   ei   = (const int*)d_in[1];
    const float* W    = (const float*)d_in[2];
    const float* att  = (const float*)d_in[3];
    const float* bias = (const float*)d_in[4];
    float* out = (float*)d_out;

    // workspace layout (~20 MB); wt first for 16 B alignment
    ushort* wt    = (ushort*)d_ws;                          // 32768 (64 KB)
    ushort* hbuf  = wt + DIN * C_OUT;                       // N*128 bf16 (12.8 MB)
    float*  s_src = (float*)(hbuf + (size_t)N_NODES * C_OUT);
    float*  s_dst = s_src + N_NODES;
    int*    head  = (int*)(s_dst + N_NODES);                // N
    int2*   nxt2  = (int2*)(head + N_NODES);                // ET int2 (6.8 MB), 8B-aligned

    wconv_kernel<<<(N_NODES + 255) / 256, 256, 0, stream>>>(W, wt, head);
    gemm_link<<<LINK_BLOCKS + GEMM_BLOCKS, 256, 0, stream>>>(
        x, wt, att, ei, hbuf, s_dst, s_src, head, nxt2);
    aggregate_kernel<<<AGG_BLOCKS, 256, 0, stream>>>(
        hbuf, head, nxt2, s_dst, s_src, bias, out);
}

// Round 8
// 88.272 us; speedup vs baseline: 1.2746x; 1.1366x over previous
//
#include <hip/hip_runtime.h>
#include <hip/hip_bf16.h>

constexpr int N_NODES = 50000;
constexpr int DIN     = 256;
constexpr int C_OUT   = 128;
constexpr int E_EDGES = 800000;
constexpr int ET      = E_EDGES + N_NODES;   // with self-loops
constexpr float NEG_SLOPE = 0.2f;

constexpr int NHI     = 196;                  // hi = dst >> 8  (50000/256)
constexpr int NCHUNK  = 416;                  // edge chunks
constexpr int EPC     = 2048;                 // edges/chunk (256 thr x 8)
constexpr int TOTCNT  = NHI * NCHUNK;         // 81536
constexpr int NSB     = (TOTCNT + 2047) / 2048;  // 40 scan blocks (<=64)
constexpr int WCONV_BLOCKS = (DIN * C_OUT) / 256; // 128
constexpr int GEMM_RPB     = 64;
constexpr int GEMM_BLOCKS  = (N_NODES + GEMM_RPB - 1) / GEMM_RPB;  // 782
constexpr int AGG_NPB      = 32;
constexpr int AGG_BLOCKS   = (N_NODES + AGG_NPB - 1) / AGG_NPB;    // 1563

typedef __attribute__((ext_vector_type(8))) short short8v;
typedef __attribute__((ext_vector_type(4))) float f32x4;

static __device__ __forceinline__ ushort f2bf(float f) {
    __hip_bfloat16 b = __float2bfloat16(f);
    return *reinterpret_cast<ushort*>(&b);
}
static __device__ __forceinline__ short f2bfs(float f) {
    __hip_bfloat16 b = __float2bfloat16(f);
    return *reinterpret_cast<short*>(&b);
}

// ---------------------------------------------------------------------------
// D1: blocks [0,NCHUNK): per-chunk hi-histogram (LDS atomics only) -> cnt[hi][c]
//     blocks [NCHUNK,+WCONV): Wt -> bf16 fragment-ordered.
// fragpos(ks,c,kgrp,col16,j) = ((ks*8+c)*64 + kgrp*16 + col16)*8 + j
// ---------------------------------------------------------------------------
__global__ __launch_bounds__(256) void count_wconv(const float* __restrict__ W,
                                                   const int* __restrict__ ei,
                                                   ushort* __restrict__ wt,
                                                   int* __restrict__ cnt) {
    __shared__ int hist[NHI];
    const int t = threadIdx.x;
    if (blockIdx.x < NCHUNK) {
        const int c = blockIdx.x;
        if (t < NHI) hist[t] = 0;
        __syncthreads();
        #pragma unroll
        for (int i = 0; i < 8; i++) {
            const int e = c * EPC + i * 256 + t;
            if (e < ET) {
                const int d = (e < E_EDGES) ? ei[E_EDGES + e] : (e - E_EDGES);
                atomicAdd(&hist[d >> 8], 1);
            }
        }
        __syncthreads();
        if (t < NHI) cnt[t * NCHUNK + c] = hist[t];
        return;
    }
    const int idx = (blockIdx.x - NCHUNK) * 256 + t;
    if (idx < DIN * C_OUT) {
        const int k = idx >> 7, col = idx & 127;
        const int ks = k >> 5, kgrp = (k >> 3) & 3, j = k & 7;
        const int cc = col >> 4, col16 = col & 15;
        wt[((ks * 8 + cc) * 64 + kgrp * 16 + col16) * 8 + j] = f2bf(W[idx]);
    }
}

// ---------------------------------------------------------------------------
// D2: blocks [0,NSB): scan stage 1 (block sums of cnt);
//     blocks [NSB,+GEMM_BLOCKS): h = x@W via MFMA (Wt in LDS per K-half,
//     fp32 x loads + in-register bf16 cvt, fused att epilogue, h bf16).
// ---------------------------------------------------------------------------
__global__ __launch_bounds__(256) void gemm_scan1(const float* __restrict__ x,
                                                  const ushort* __restrict__ wt,
                                                  const float* __restrict__ att,
                                                  const int* __restrict__ cnt,
                                                  int* __restrict__ bsum,
                                                  ushort* __restrict__ hb,
                                                  float* __restrict__ s_dst,
                                                  float* __restrict__ s_src) {
    __shared__ ushort lw[DIN * C_OUT / 2];   // 32 KB, one K-half fragment-ordered
    __shared__ int wsum[4];
    const int t = threadIdx.x;

    if (blockIdx.x < NSB) {                  // ---- scan stage 1 ----
        const int b = blockIdx.x;
        const int i0 = b * 2048 + t * 8;
        int s = 0;
        #pragma unroll
        for (int j = 0; j < 8; j++) { const int i = i0 + j; if (i < TOTCNT) s += cnt[i]; }
        #pragma unroll
        for (int off = 32; off; off >>= 1) s += __shfl_xor(s, off);
        if ((t & 63) == 0) wsum[t >> 6] = s;
        __syncthreads();
        if (t == 0) bsum[b] = wsum[0] + wsum[1] + wsum[2] + wsum[3];
        return;
    }

    // ---- GEMM path ----
    const int gb = blockIdx.x - NSB;
    const int lane = t & 63, wv = t >> 6;
    const int col16 = lane & 15, kgrp = lane >> 4;
    const int rowbase = gb * GEMM_RPB + wv * 16;
    int r0 = rowbase + col16; if (r0 >= N_NODES) r0 = N_NODES - 1;
    const float* xr0 = x + (size_t)r0 * DIN + kgrp * 8;

    f32x4 acc[8] = {};
    const short8v* lwf = (const short8v*)lw;
    #pragma unroll
    for (int ph = 0; ph < 2; ph++) {
        if (ph) __syncthreads();             // protect LDS before overwrite
        {   // stage this K-half of Wt (32 KB contiguous)
            const uint4* src = (const uint4*)(wt + ph * (DIN * C_OUT / 2));
            uint4* dst = (uint4*)lw;
            #pragma unroll
            for (int i = 0; i < 8; i++) dst[t + i * 256] = src[t + i * 256];
        }
        // hoisted fp32 A loads + in-register bf16 cvt (independent of LDS)
        short8v A0[4];
        #pragma unroll
        for (int ks = 0; ks < 4; ks++) {
            const int kg = ph * 4 + ks;
            const float4 v0 = *(const float4*)(xr0 + kg * 32);
            const float4 v1 = *(const float4*)(xr0 + kg * 32 + 4);
            short8v a;
            a[0] = f2bfs(v0.x); a[1] = f2bfs(v0.y); a[2] = f2bfs(v0.z); a[3] = f2bfs(v0.w);
            a[4] = f2bfs(v1.x); a[5] = f2bfs(v1.y); a[6] = f2bfs(v1.z); a[7] = f2bfs(v1.w);
            A0[ks] = a;
        }
        __syncthreads();
        #pragma unroll
        for (int ks = 0; ks < 4; ks++) {
            #pragma unroll
            for (int c = 0; c < 8; c++) {
                const short8v bfr = lwf[(ks * 8 + c) * 64 + lane];
                acc[c] = __builtin_amdgcn_mfma_f32_16x16x32_bf16(A0[ks], bfr, acc[c], 0, 0, 0);
            }
        }
    }

    float attd[8], atts[8];
    #pragma unroll
    for (int c = 0; c < 8; c++) {
        attd[c] = att[c * 16 + col16];
        atts[c] = att[C_OUT + c * 16 + col16];
    }
    #pragma unroll
    for (int j = 0; j < 4; j++) {
        const int row = rowbase + kgrp * 4 + j;   // C/D: col=lane&15, row=(lane>>4)*4+j
        const bool ok = (row < N_NODES);
        float pd = 0.f, ps = 0.f;
        #pragma unroll
        for (int c = 0; c < 8; c++) {
            const float hv = acc[c][j];
            pd += hv * attd[c];
            ps += hv * atts[c];
            if (ok) hb[(size_t)row * C_OUT + c * 16 + col16] = f2bf(hv);
        }
        #pragma unroll
        for (int off = 1; off < 16; off <<= 1) {
            pd += __shfl_xor(pd, off);
            ps += __shfl_xor(ps, off);
        }
        if (col16 == 0 && ok) { s_dst[row] = pd; s_src[row] = ps; }
    }
}

// ---------------------------------------------------------------------------
// D3: scan stage 2 — one wave scans the NSB block sums.
// ---------------------------------------------------------------------------
__global__ void scan_mid(const int* __restrict__ bsum, int* __restrict__ bbase) {
    const int lane = threadIdx.x;   // 64 threads
    const int v = (lane < NSB) ? bsum[lane] : 0;
    int x = v;
    #pragma unroll
    for (int off = 1; off < 64; off <<= 1) {
        const int y = __shfl_up(x, off);
        if (lane >= off) x += y;
    }
    if (lane < NSB) bbase[lane] = x - v;   // exclusive
}

// ---------------------------------------------------------------------------
// D4: scan stage 3 — finalize exclusive scan of cnt in place.
// ---------------------------------------------------------------------------
__global__ __launch_bounds__(256) void scan_fin(int* __restrict__ cnt,
                                                const int* __restrict__ bbase) {
    __shared__ int wsum[4];
    const int t = threadIdx.x, b = blockIdx.x;
    const int lane = t & 63, wv = t >> 6;
    const int i0 = b * 2048 + t * 8;
    int c[8]; int ts = 0;
    #pragma unroll
    for (int j = 0; j < 8; j++) {
        const int i = i0 + j;
        c[j] = (i < TOTCNT) ? cnt[i] : 0;
        ts += c[j];
    }
    int x = ts;
    #pragma unroll
    for (int off = 1; off < 64; off <<= 1) {
        const int y = __shfl_up(x, off);
        if (lane >= off) x += y;
    }
    if (lane == 63) wsum[wv] = x;
    __syncthreads();
    int wbase = 0;
    #pragma unroll
    for (int w = 0; w < 4; w++) if (w < wv) wbase += wsum[w];
    int base = bbase[b] + wbase + (x - ts);
    #pragma unroll
    for (int j = 0; j < 8; j++) {
        const int i = i0 + j;
        if (i < TOTCNT) cnt[i] = base;
        base += c[j];
    }
}

// ---------------------------------------------------------------------------
// D5: partition edges into hi-grouped ebuf[{src,dst}] (LDS cursors only).
// ---------------------------------------------------------------------------
__global__ __launch_bounds__(256) void part_kernel(const int* __restrict__ ei,
                                                   const int* __restrict__ sco,
                                                   int2* __restrict__ ebuf) {
    __shared__ int basel[NHI];
    __shared__ int curl[NHI];
    const int t = threadIdx.x, c = blockIdx.x;
    if (t < NHI) { basel[t] = sco[t * NCHUNK + c]; curl[t] = 0; }
    __syncthreads();
    #pragma unroll
    for (int i = 0; i < 8; i++) {
        const int e = c * EPC + i * 256 + t;
        if (e < ET) {
            int s, d;
            if (e < E_EDGES) { s = ei[e]; d = ei[E_EDGES + e]; }
            else             { s = e - E_EDGES; d = s; }
            const int hi = d >> 8;
            const int r = atomicAdd(&curl[hi], 1);   // LDS atomic (fast)
            ebuf[basel[hi] + r] = make_int2(s, d);
        }
    }
}

// ---------------------------------------------------------------------------
// D6: per-hi finalize: LDS histogram over lo, LDS scan, LDS-cursor scatter
//     -> CSR offsets[] + esrc[] (writes dense within own segment).
// ---------------------------------------------------------------------------
__global__ __launch_bounds__(256) void final_kernel(const int* __restrict__ sco,
                                                    const int2* __restrict__ ebuf,
                                                    int* __restrict__ offsets,
                                                    int* __restrict__ esrc) {
    __shared__ int histl[256], sA[256], sE[256], curl[256];
    const int t = threadIdx.x, hi = blockIdx.x;
    const int segbase = sco[hi * NCHUNK];
    const int segend  = (hi == NHI - 1) ? ET : sco[(hi + 1) * NCHUNK];
    histl[t] = 0;
    if (hi == 0 && t == 0) offsets[N_NODES] = ET;
    __syncthreads();
    for (int k = segbase + t; k < segend; k += 256)
        atomicAdd(&histl[ebuf[k].y & 255], 1);
    __syncthreads();
    const int v = histl[t];
    sA[t] = v;
    __syncthreads();
    #pragma unroll
    for (int off = 1; off < 256; off <<= 1) {   // Hillis-Steele inclusive
        const int y = (t >= off) ? sA[t - off] : 0;
        __syncthreads();
        sA[t] += y;
        __syncthreads();
    }
    sE[t] = sA[t] - v;   // exclusive
    curl[t] = 0;
    const int node = hi * 256 + t;
    if (node < N_NODES) offsets[node] = segbase + sE[t];
    __syncthreads();
    for (int k = segbase + t; k < segend; k += 256) {
        const int2 e2 = ebuf[k];
        const int lo = e2.y & 255;
        const int r = atomicAdd(&curl[lo], 1);   // LDS atomic
        esrc[segbase + sE[lo] + r] = e2.x;
    }
}

// ---------------------------------------------------------------------------
// D7: aggregation over CSR. 8 nodes/wave (8-lane groups; 2x uint4/lane =
// full 256 B bf16 row). Sequential esrc reads (broadcast within group).
// Softmax without max-subtraction (|alpha| small, fp32-safe, ratios exact).
// ---------------------------------------------------------------------------
__global__ __launch_bounds__(256) void aggregate_kernel(
    const ushort* __restrict__ hb, const int* __restrict__ offsets,
    const int* __restrict__ esrc, const float* __restrict__ s_dst,
    const float* __restrict__ s_src, const float* __restrict__ bias,
    float* __restrict__ out) {
    const int t = threadIdx.x;
    const int wv = t >> 6, lane = t & 63;
    const int sub = lane >> 3, l8 = lane & 7;          // 8 groups of 8 lanes
    const int node = blockIdx.x * AGG_NPB + wv * 8 + sub;
    const bool valid = (node < N_NODES);

    const int beg = valid ? offsets[node] : 0;
    const int end = valid ? offsets[node + 1] : 0;
    const float sd = valid ? s_dst[node] : 0.f;
    float den = 0.f;
    float acc[16] = {};
    const uint4* __restrict__ h4 = (const uint4*)hb;

    for (int e = beg; e < end; e++) {
        const int s = esrc[e];                         // broadcast in group
        float a = sd + s_src[s];
        a = (a > 0.f) ? a : NEG_SLOPE * a;
        const float w = __expf(a);
        den += w;
        const uint4 hv0 = h4[(size_t)s * 16 + l8];
        const uint4 hv1 = h4[(size_t)s * 16 + 8 + l8];
        acc[0]  += w * __uint_as_float(hv0.x << 16);
        acc[1]  += w * __uint_as_float(hv0.x & 0xffff0000u);
        acc[2]  += w * __uint_as_float(hv0.y << 16);
        acc[3]  += w * __uint_as_float(hv0.y & 0xffff0000u);
        acc[4]  += w * __uint_as_float(hv0.z << 16);
        acc[5]  += w * __uint_as_float(hv0.z & 0xffff0000u);
        acc[6]  += w * __uint_as_float(hv0.w << 16);
        acc[7]  += w * __uint_as_float(hv0.w & 0xffff0000u);
        acc[8]  += w * __uint_as_float(hv1.x << 16);
        acc[9]  += w * __uint_as_float(hv1.x & 0xffff0000u);
        acc[10] += w * __uint_as_float(hv1.y << 16);
        acc[11] += w * __uint_as_float(hv1.y & 0xffff0000u);
        acc[12] += w * __uint_as_float(hv1.z << 16);
        acc[13] += w * __uint_as_float(hv1.z & 0xffff0000u);
        acc[14] += w * __uint_as_float(hv1.w << 16);
        acc[15] += w * __uint_as_float(hv1.w & 0xffff0000u);
    }
    if (!valid) return;
    const float inv = 1.f / (den + 1e-16f);
    float* op = out + (size_t)node * C_OUT;
    #pragma unroll
    for (int half = 0; half < 2; half++) {
        const int base = half * 64 + l8 * 8;
        const float4 b0 = *(const float4*)(bias + base);
        const float4 b1 = *(const float4*)(bias + base + 4);
        float4 o0 = make_float4(acc[half * 8 + 0] * inv + b0.x, acc[half * 8 + 1] * inv + b0.y,
                                acc[half * 8 + 2] * inv + b0.z, acc[half * 8 + 3] * inv + b0.w);
        float4 o1 = make_float4(acc[half * 8 + 4] * inv + b1.x, acc[half * 8 + 5] * inv + b1.y,
                                acc[half * 8 + 6] * inv + b1.z, acc[half * 8 + 7] * inv + b1.w);
        *(float4*)(op + base)     = o0;
        *(float4*)(op + base + 4) = o1;
    }
}

// ---------------------------------------------------------------------------
extern "C" void kernel_launch(void* const* d_in, const int* in_sizes, int n_in,
                              void* d_out, int out_size, void* d_ws, size_t ws_size,
                              hipStream_t stream) {
    const float* x    = (const float*)d_in[0];
    const int*   ei   = (const int*)d_in[1];
    const float* W    = (const float*)d_in[2];
    const float* att  = (const float*)d_in[3];
    const float* bias = (const float*)d_in[4];
    float* out = (float*)d_out;

    // workspace layout (~24 MB); wt first for 16 B alignment, ebuf 8 B-aligned
    ushort* wt      = (ushort*)d_ws;                         // 32768 (64 KB)
    ushort* hbuf    = wt + DIN * C_OUT;                      // N*128 bf16 (12.8 MB)
    int2*   ebuf    = (int2*)(hbuf + (size_t)N_NODES * C_OUT); // ET int2 (6.8 MB)
    float*  s_src   = (float*)(ebuf + ET);
    float*  s_dst   = s_src + N_NODES;
    int*    offsets = (int*)(s_dst + N_NODES);               // N+1 (pad to +2)
    int*    esrc    = offsets + N_NODES + 2;                 // ET
    int*    cnt     = esrc + ET;                             // TOTCNT
    int*    bsum    = cnt + TOTCNT;                          // NSB
    int*    bbase   = bsum + 64;                             // NSB

    count_wconv<<<NCHUNK + WCONV_BLOCKS, 256, 0, stream>>>(W, ei, wt, cnt);
    gemm_scan1<<<NSB + GEMM_BLOCKS, 256, 0, stream>>>(x, wt, att, cnt, bsum,
                                                      hbuf, s_dst, s_src);
    scan_mid<<<1, 64, 0, stream>>>(bsum, bbase);
    scan_fin<<<NSB, 256, 0, stream>>>(cnt, bbase);
    part_kernel<<<NCHUNK, 256, 0, stream>>>(ei, cnt, ebuf);
    final_kernel<<<NHI, 256, 0, stream>>>(cnt, ebuf, offsets, esrc);
    aggregate_kernel<<<AGG_BLOCKS, 256, 0, stream>>>(
        hbuf, offsets, esrc, s_dst, s_src, bias, out);
}